// Round 1
// baseline (17277.730 us; speedup 1.0000x reference)
//
#include <hip/hip_runtime.h>
#include <hip/hip_cooperative_groups.h>
#include <cstddef>
#include <cstdint>

namespace cg = cooperative_groups;

// CustomLSTM: T=512, B=64, I=H=1024, L=2. fp32 in/out, bf16 MFMA internally.
#define T_LEN   512
#define BATCH   64
#define IN_DIM  1024
#define HID     1024
#define GATES   4096
#define NLAYERS 2
#define TCHUNK  64
#define BH      (BATCH * HID)
#define RBLK    64              // persistent-recurrence blocks; 16 hidden units each

typedef __bf16 bf16;
typedef __bf16 bf16x8 __attribute__((ext_vector_type(8)));
typedef float  f32x4  __attribute__((ext_vector_type(4)));

// ---------------------------------------------------------------------------
// fp32 -> bf16 (RNE), vectorized. n4 = n/4.
// ---------------------------------------------------------------------------
__global__ __launch_bounds__(256) void cvt_bf16(const float* __restrict__ in,
                                                bf16* __restrict__ out, int n4) {
    int i = blockIdx.x * blockDim.x + threadIdx.x;
    if (i >= n4) return;
    float4 v = ((const float4*)in)[i];
    bf16 o[4] = {(bf16)v.x, (bf16)v.y, (bf16)v.z, (bf16)v.w};
    *(uint2*)(out + 4 * (size_t)i) = *(uint2*)o;
}

// ---------------------------------------------------------------------------
// Input projection GEMM (NT, bf16 MFMA): C[m][n] = A[m][:]·W[n][:] + bias[n]
// M=TCHUNK*B=4096, N=GATES=4096, K=1024. 128x128 tile, BK=32, 256 thr, 4 waves
// each computing 64x64 as 4x4 grid of mfma_f32_16x16x32_bf16.
// ---------------------------------------------------------------------------
template <bool AF32>
__global__ __launch_bounds__(256) void gemm_xin(
    const void* __restrict__ Aptr, const bf16* __restrict__ W,
    const float* __restrict__ bih, const float* __restrict__ bhh,
    float* __restrict__ C)
{
    __shared__ bf16 As[128 * 40];   // [m][k], pad 32->40 breaks b128 conflicts
    __shared__ bf16 Bs[128 * 40];   // [n][k]

    const int m0 = blockIdx.y * 128;
    const int n0 = blockIdx.x * 128;
    const int tid  = threadIdx.x;
    const int lane = tid & 63;
    const int wv   = tid >> 6;          // 0..3
    const int wm   = (wv & 1) * 64;
    const int wn   = (wv >> 1) * 64;
    const int quad = lane >> 4;         // 0..3
    const int l16  = lane & 15;

    f32x4 acc[4][4] = {};

    for (int k0 = 0; k0 < IN_DIM; k0 += 32) {
        if constexpr (AF32) {
            const float* A = (const float*)Aptr;
            const int row = tid >> 3;            // 0..31
            const int ko  = (tid & 7) * 4;       // 0..28
            #pragma unroll
            for (int p = 0; p < 4; ++p) {
                int r = row + 32 * p;
                float4 v = *(const float4*)(A + (size_t)(m0 + r) * IN_DIM + k0 + ko);
                bf16 o[4] = {(bf16)v.x, (bf16)v.y, (bf16)v.z, (bf16)v.w};
                *(uint2*)&As[r * 40 + ko] = *(uint2*)o;
            }
        } else {
            const bf16* A = (const bf16*)Aptr;
            const int row = tid >> 2;            // 0..63
            const int ko  = (tid & 3) * 8;       // 0,8,16,24
            *(uint4*)&As[row * 40 + ko] =
                *(const uint4*)(A + (size_t)(m0 + row) * IN_DIM + k0 + ko);
            *(uint4*)&As[(row + 64) * 40 + ko] =
                *(const uint4*)(A + (size_t)(m0 + row + 64) * IN_DIM + k0 + ko);
        }
        {
            const int row = tid >> 2;
            const int ko  = (tid & 3) * 8;
            *(uint4*)&Bs[row * 40 + ko] =
                *(const uint4*)(W + (size_t)(n0 + row) * IN_DIM + k0 + ko);
            *(uint4*)&Bs[(row + 64) * 40 + ko] =
                *(const uint4*)(W + (size_t)(n0 + row + 64) * IN_DIM + k0 + ko);
        }
        __syncthreads();

        bf16x8 af[4], bfr[4];
        #pragma unroll
        for (int t = 0; t < 4; ++t) {
            af[t]  = *(const bf16x8*)&As[(wm + t * 16 + l16) * 40 + quad * 8];
            bfr[t] = *(const bf16x8*)&Bs[(wn + t * 16 + l16) * 40 + quad * 8];
        }
        #pragma unroll
        for (int mt = 0; mt < 4; ++mt)
            #pragma unroll
            for (int nt = 0; nt < 4; ++nt)
                acc[mt][nt] = __builtin_amdgcn_mfma_f32_16x16x32_bf16(
                    af[mt], bfr[nt], acc[mt][nt], 0, 0, 0);
        __syncthreads();
    }

    #pragma unroll
    for (int nt = 0; nt < 4; ++nt) {
        int col = n0 + wn + nt * 16 + l16;
        float bias = bih[col] + bhh[col];
        #pragma unroll
        for (int mt = 0; mt < 4; ++mt) {
            #pragma unroll
            for (int r = 0; r < 4; ++r) {
                int row = m0 + wm + mt * 16 + quad * 4 + r;
                C[(size_t)row * GATES + col] = acc[mt][nt][r] + bias;
            }
        }
    }
}

// ---------------------------------------------------------------------------
// Persistent recurrence: ONE cooperative launch per 64-step chunk.
// 64 blocks; block bk owns hidden units j0=16bk..+15 -> 64 gate rows
// (local row c (0..63) <-> gate row (c>>4)*1024 + j0 + (c&15)).
// wh slice (64x1024 bf16 = 128 KiB) staged in LDS ONCE per chunk,
// XOR-swizzled in 16B units (k16 ^ (row&7)) so b128 reads are 2-way (free).
// 4 waves; wave wv owns batches 16wv..+15 (MFMA M). Col-tile ct = gate type,
// so each thread holds i,f,g,o of the same (batch,unit) -> no LDS exchange.
// c state lives in registers across the whole chunk. grid.sync() per step.
// h ping-pong in global bf16 (all-to-all across blocks).
// ---------------------------------------------------------------------------
__global__ __launch_bounds__(256) void lstm_chunk(
    const bf16*  __restrict__ wh,      // [4H][H] bf16
    const float* __restrict__ xg,      // [TCHUNK][B][4H] fp32
    float*       __restrict__ cbuf,    // [B][H]
    float*       __restrict__ hf32,    // [B][H] (final h only)
    bf16*        __restrict__ hping,   // [2][B][H] bf16
    bf16*        __restrict__ seq_bf,  // [T][B][H] or null (layer 0)
    float*       __restrict__ seq_f32, // [T][B][H] or null (layer 1)
    int t0)
{
    __shared__ bf16 Bs[64 * 1024];     // 128 KiB, swizzled

    cg::grid_group grid = cg::this_grid();

    const int bk   = blockIdx.x;
    const int j0   = bk * 16;
    const int tid  = threadIdx.x;
    const int lane = tid & 63;
    const int wv   = tid >> 6;
    const int m0   = wv * 16;          // batch base for this wave
    const int quad = lane >> 4;
    const int l16  = lane & 15;
    const int xm   = l16 & 7;          // read-side swizzle mask (row&7 == l16&7)

    // stage wh slice: 64 rows x 128 uint4, coalesced; swizzled LDS dest
    #pragma unroll
    for (int i = 0; i < 32; ++i) {
        int flat = i * 256 + tid;       // 0..8191
        int row  = flat >> 7;
        int k16  = flat & 127;
        int gr   = (row >> 4) * 1024 + j0 + (row & 15);
        *(uint4*)&Bs[(row * 128 + (k16 ^ (row & 7))) * 8] =
            *(const uint4*)(wh + (size_t)gr * HID + k16 * 8);
    }

    const int bb = m0 + quad * 4;       // this thread: batches bb..bb+3
    const int uu = j0 + l16;            // this thread's hidden unit

    // cell state in registers for the whole chunk
    float c[4];
    #pragma unroll
    for (int r = 0; r < 4; ++r) c[r] = cbuf[(size_t)(bb + r) * HID + uu];

    __syncthreads();

    const bf16* bbase = &Bs[(size_t)l16 * 1024];

    for (int tt = 0; tt < TCHUNK; ++tt) {
        const int t = t0 + tt;
        const bf16*  hin  = hping + (size_t)(t & 1) * BH;
        bf16*        hout = hping + (size_t)(1 - (t & 1)) * BH;
        const float* xgt  = xg + (size_t)tt * BATCH * GATES;

        // xin: issue loads now, consume AFTER the MFMA loop (latency hidden)
        float xv[4][4];
        #pragma unroll
        for (int ct = 0; ct < 4; ++ct)
            #pragma unroll
            for (int r = 0; r < 4; ++r)
                xv[ct][r] = xgt[(size_t)(bb + r) * GATES + ct * 1024 + uu];

        f32x4 acc[4] = {};              // 4 independent MFMA chains (gate types)
        const bf16* aptr = hin + (size_t)(m0 + l16) * HID + quad * 8;
        #pragma unroll 8
        for (int k0 = 0; k0 < HID; k0 += 32) {
            bf16x8 a = *(const bf16x8*)(aptr + k0);
            int us = (quad + (k0 >> 3)) ^ xm;
            #pragma unroll
            for (int ct = 0; ct < 4; ++ct) {
                bf16x8 b = *(const bf16x8*)(bbase + ct * 16 * 1024 + us * 8);
                acc[ct] = __builtin_amdgcn_mfma_f32_16x16x32_bf16(a, b, acc[ct], 0, 0, 0);
            }
        }

        const bool lastt = (t == T_LEN - 1);
        #pragma unroll
        for (int r = 0; r < 4; ++r) {
            float gi = acc[0][r] + xv[0][r];
            float gf = acc[1][r] + xv[1][r];
            float gg = acc[2][r] + xv[2][r];
            float go = acc[3][r] + xv[3][r];
            float si = 1.f / (1.f + expf(-gi));
            float sf = 1.f / (1.f + expf(-gf));
            float so = 1.f / (1.f + expf(-go));
            float cv = sf * c[r] + si * tanhf(gg);
            float hv = so * tanhf(cv);
            c[r] = cv;
            size_t idx = (size_t)(bb + r) * HID + uu;
            hout[idx] = (bf16)hv;
            if (seq_bf)  seq_bf[(size_t)t * BH + idx] = (bf16)hv;
            if (seq_f32) seq_f32[(size_t)t * BH + idx] = hv;
            if (lastt)   hf32[idx] = hv;
        }
        if (tt != TCHUNK - 1) grid.sync();
    }

    #pragma unroll
    for (int r = 0; r < 4; ++r)
        cbuf[(size_t)(bb + r) * HID + uu] = c[r];
}

// ---------------------------------------------------------------------------
extern "C" void kernel_launch(void* const* d_in, const int* in_sizes, int n_in,
                              void* d_out, int out_size, void* d_ws, size_t ws_size,
                              hipStream_t stream) {
    const float* x    = (const float*)d_in[0];
    const float* w_ih = (const float*)d_in[1];
    const float* w_hh = (const float*)d_in[2];
    const float* b_ih = (const float*)d_in[3];
    const float* b_hh = (const float*)d_in[4];
    float* out = (float*)d_out;

    // ws layout (fp32 region first for alignment):
    //   xin    : TCHUNK*B*4H fp32 = 64 MB
    //   cbuf   : B*H fp32, hf32: B*H fp32
    //   seq1bf : T*B*H bf16 = 64 MB   (layer-0 output, layer-1 GEMM input)
    //   wibf   : 4H*I bf16 (per-layer reuse), whbf: 4H*H bf16
    //   hping  : 2 * B*H bf16
    float* xin  = (float*)d_ws;
    float* cbuf = xin + (size_t)TCHUNK * BATCH * GATES;
    float* hf32 = cbuf + (size_t)BATCH * HID;
    bf16* seq1bf = (bf16*)(hf32 + (size_t)BATCH * HID);
    bf16* wibf   = seq1bf + (size_t)T_LEN * BATCH * HID;
    bf16* whbf   = wibf + (size_t)GATES * IN_DIM;
    bf16* hping  = whbf + (size_t)GATES * HID;

    const size_t seqE = (size_t)T_LEN * BATCH * HID;
    const size_t BHs  = (size_t)BATCH * HID;

    for (int l = 0; l < NLAYERS; ++l) {
        const float* wi = w_ih + (size_t)l * GATES * IN_DIM;
        const float* wh = w_hh + (size_t)l * GATES * HID;
        const float* bi = b_ih + (size_t)l * GATES;
        const float* bh = b_hh + (size_t)l * GATES;

        // weights -> bf16 (per-layer buffers, reused across layers)
        cvt_bf16<<<(GATES * IN_DIM / 4 + 255) / 256, 256, 0, stream>>>(wi, wibf, GATES * IN_DIM / 4);
        cvt_bf16<<<(GATES * HID / 4 + 255) / 256, 256, 0, stream>>>(wh, whbf, GATES * HID / 4);

        hipMemsetAsync(hping, 0, BHs * sizeof(bf16), stream);      // h(-1)=0
        hipMemsetAsync(cbuf, 0, BHs * sizeof(float), stream);      // c(-1)=0

        for (int ch = 0; ch < T_LEN / TCHUNK; ++ch) {
            // input projection for this chunk: [4096 x 4096 x 1024]
            if (l == 0) {
                const float* Ab = x + (size_t)ch * TCHUNK * BATCH * IN_DIM;
                gemm_xin<true><<<dim3(GATES / 128, TCHUNK * BATCH / 128), 256, 0, stream>>>(
                    Ab, wibf, bi, bh, xin);
            } else {
                const bf16* Ab = seq1bf + (size_t)ch * TCHUNK * BATCH * HID;
                gemm_xin<false><<<dim3(GATES / 128, TCHUNK * BATCH / 128), 256, 0, stream>>>(
                    Ab, wibf, bi, bh, xin);
            }
            // persistent recurrence over the 64 timesteps of this chunk
            int t0 = ch * TCHUNK;
            const bf16*  whc = whbf;
            const float* xgc = xin;
            bf16*  sb = (l == 0) ? seq1bf : nullptr;
            float* sf = (l == 1) ? out : nullptr;
            void* args[8] = { (void*)&whc, (void*)&xgc, (void*)&cbuf, (void*)&hf32,
                              (void*)&hping, (void*)&sb, (void*)&sf, (void*)&t0 };
            hipLaunchCooperativeKernel((void*)lstm_chunk, dim3(RBLK), dim3(256),
                                       args, 0, stream);
        }
        hipMemcpyAsync(out + seqE + (size_t)l * BHs, hf32, BHs * sizeof(float),
                       hipMemcpyDeviceToDevice, stream);
        hipMemcpyAsync(out + seqE + (size_t)(NLAYERS + l) * BHs, cbuf, BHs * sizeof(float),
                       hipMemcpyDeviceToDevice, stream);
    }
}

// Round 3
// 12357.430 us; speedup vs baseline: 1.3982x; 1.3982x over previous
//
#include <hip/hip_runtime.h>
#include <cstddef>
#include <cstdint>

// CustomLSTM: T=512, B=64, I=H=1024, L=2. fp32 in/out, bf16 MFMA internally.
#define T_LEN   512
#define BATCH   64
#define IN_DIM  1024
#define HID     1024
#define GATES   4096
#define NLAYERS 2
#define TCHUNK  64
#define BH      (BATCH * HID)
#define RBLK    256             // persistent-recurrence blocks; 4 hidden units each

typedef __bf16 bf16;
typedef __bf16 bf16x8 __attribute__((ext_vector_type(8)));
typedef float  f32x4  __attribute__((ext_vector_type(4)));

// ---------------------------------------------------------------------------
// fp32 -> bf16 (RNE), vectorized. n4 = n/4.
// ---------------------------------------------------------------------------
__global__ __launch_bounds__(256) void cvt_bf16(const float* __restrict__ in,
                                                bf16* __restrict__ out, int n4) {
    int i = blockIdx.x * blockDim.x + threadIdx.x;
    if (i >= n4) return;
    float4 v = ((const float4*)in)[i];
    bf16 o[4] = {(bf16)v.x, (bf16)v.y, (bf16)v.z, (bf16)v.w};
    *(uint2*)(out + 4 * (size_t)i) = *(uint2*)o;
}

// ---------------------------------------------------------------------------
// Input projection GEMM (NT, bf16 MFMA): C[m][n] = A[m][:]·W[n][:] + bias[n]
// M=TCHUNK*B=4096, N=GATES=4096, K=1024. 128x128 tile, BK=32, 256 thr, 4 waves
// each computing 64x64 as 4x4 grid of mfma_f32_16x16x32_bf16.
// ---------------------------------------------------------------------------
template <bool AF32>
__global__ __launch_bounds__(256) void gemm_xin(
    const void* __restrict__ Aptr, const bf16* __restrict__ W,
    const float* __restrict__ bih, const float* __restrict__ bhh,
    float* __restrict__ C)
{
    __shared__ bf16 As[128 * 40];   // [m][k], pad 32->40 breaks b128 conflicts
    __shared__ bf16 Bs[128 * 40];   // [n][k]

    const int m0 = blockIdx.y * 128;
    const int n0 = blockIdx.x * 128;
    const int tid  = threadIdx.x;
    const int lane = tid & 63;
    const int wv   = tid >> 6;          // 0..3
    const int wm   = (wv & 1) * 64;
    const int wn   = (wv >> 1) * 64;
    const int quad = lane >> 4;         // 0..3
    const int l16  = lane & 15;

    f32x4 acc[4][4] = {};

    for (int k0 = 0; k0 < IN_DIM; k0 += 32) {
        if constexpr (AF32) {
            const float* A = (const float*)Aptr;
            const int row = tid >> 3;            // 0..31
            const int ko  = (tid & 7) * 4;       // 0..28
            #pragma unroll
            for (int p = 0; p < 4; ++p) {
                int r = row + 32 * p;
                float4 v = *(const float4*)(A + (size_t)(m0 + r) * IN_DIM + k0 + ko);
                bf16 o[4] = {(bf16)v.x, (bf16)v.y, (bf16)v.z, (bf16)v.w};
                *(uint2*)&As[r * 40 + ko] = *(uint2*)o;
            }
        } else {
            const bf16* A = (const bf16*)Aptr;
            const int row = tid >> 2;            // 0..63
            const int ko  = (tid & 3) * 8;       // 0,8,16,24
            *(uint4*)&As[row * 40 + ko] =
                *(const uint4*)(A + (size_t)(m0 + row) * IN_DIM + k0 + ko);
            *(uint4*)&As[(row + 64) * 40 + ko] =
                *(const uint4*)(A + (size_t)(m0 + row + 64) * IN_DIM + k0 + ko);
        }
        {
            const int row = tid >> 2;
            const int ko  = (tid & 3) * 8;
            *(uint4*)&Bs[row * 40 + ko] =
                *(const uint4*)(W + (size_t)(n0 + row) * IN_DIM + k0 + ko);
            *(uint4*)&Bs[(row + 64) * 40 + ko] =
                *(const uint4*)(W + (size_t)(n0 + row + 64) * IN_DIM + k0 + ko);
        }
        __syncthreads();

        bf16x8 af[4], bfr[4];
        #pragma unroll
        for (int t = 0; t < 4; ++t) {
            af[t]  = *(const bf16x8*)&As[(wm + t * 16 + l16) * 40 + quad * 8];
            bfr[t] = *(const bf16x8*)&Bs[(wn + t * 16 + l16) * 40 + quad * 8];
        }
        #pragma unroll
        for (int mt = 0; mt < 4; ++mt)
            #pragma unroll
            for (int nt = 0; nt < 4; ++nt)
                acc[mt][nt] = __builtin_amdgcn_mfma_f32_16x16x32_bf16(
                    af[mt], bfr[nt], acc[mt][nt], 0, 0, 0);
        __syncthreads();
    }

    #pragma unroll
    for (int nt = 0; nt < 4; ++nt) {
        int col = n0 + wn + nt * 16 + l16;
        float bias = bih[col] + bhh[col];
        #pragma unroll
        for (int mt = 0; mt < 4; ++mt) {
            #pragma unroll
            for (int r = 0; r < 4; ++r) {
                int row = m0 + wm + mt * 16 + quad * 4 + r;
                C[(size_t)row * GATES + col] = acc[mt][nt][r] + bias;
            }
        }
    }
}

// ---------------------------------------------------------------------------
// Persistent recurrence, coherence-minimal version.
// 256 blocks (cooperative); block bk owns hidden units j0=4bk..+3 -> 16 gate
// rows, staged in LDS ONCE per 64-step chunk.
// Per step: 1 MFMA col-tile per wave, K split into 4 independent chains (ILP).
// Gate exchange via per-wave sg region (intra-wave DS ordering, no barrier).
// Cell state c lives in a register all chunk.
// Cross-block h exchange WITHOUT L2 inv/wb:
//  - h lives in a 64-slot rotating buffer: every address is written once and
//    read once per launch (slot s: write at step s-1, read at step s; slot 0:
//    read at step 0, write at step 63 for the next launch) -> no cache can
//    hold a stale copy when read; kernel-launch acquire handles cross-launch.
//  - h stores are relaxed agent-scope atomic stores (write-through to LLC).
//  - barrier: s_waitcnt vmcnt(0) + __syncthreads (drain all waves' stores),
//    one relaxed agent atomicAdd per block, bounded relaxed spin + s_sleep.
//    The spin guard makes any deadlock degrade to a wrong answer (kernel
//    terminates) instead of a GPU hang.
// ---------------------------------------------------------------------------
__global__ __launch_bounds__(256) void lstm_chunk(
    const bf16*  __restrict__ wh,      // [4H][H] bf16
    const float* __restrict__ xg,      // [TCHUNK][B][4H] fp32
    float*       __restrict__ cbuf,    // [B][H]
    float*       __restrict__ hf32,    // [B][H] (written at t==T_LEN-1 only)
    bf16*        __restrict__ hrot,    // [TCHUNK][B][H] rotating h
    bf16*        __restrict__ seq_bf,  // [T][B][H] or null (layer 0)
    float*       __restrict__ seq_f32, // [T][B][H] or null (layer 1)
    unsigned*    __restrict__ bar,     // zeroed before launch
    int t0)
{
    __shared__ bf16  Bs[16 * 1032];    // wh slice, pad 1024->1032
    __shared__ float sg[4 * 272];      // per-wave gate tile, stride 17

    const int bk   = blockIdx.x;
    const int j0   = bk * 4;
    const int tid  = threadIdx.x;
    const int lane = tid & 63;
    const int wv   = tid >> 6;
    const int m0   = wv * 16;          // batch base for this wave
    const int quad = lane >> 4;
    const int l16  = lane & 15;

    // stage wh rows once: local row = type*4+u -> gate row type*1024 + j0 + u
    #pragma unroll
    for (int i = 0; i < 8; ++i) {
        int flat = i * 256 + tid;       // 0..2047 (16 rows x 128 uint4)
        int row  = flat >> 7;
        int k16  = flat & 127;
        int grr  = (row >> 2) * 1024 + j0 + (row & 3);
        *(uint4*)&Bs[row * 1032 + k16 * 8] =
            *(const uint4*)(wh + (size_t)grr * HID + k16 * 8);
    }

    // this thread's cell: batch cb, unit cu (one cell per thread, all steps)
    const int cb = m0 + l16;
    const int cu = j0 + quad;
    float c = cbuf[(size_t)cb * HID + cu];

    // MFMA D mapping: row = quad*4+r (batch bb+r), col = l16 -> gate row gr
    const int gr = (l16 >> 2) * 1024 + j0 + (l16 & 3);
    const int bb = m0 + quad * 4;

    // prologue xin for tt=0 (prefetched one step ahead thereafter)
    float xv0 = xg[(size_t)(bb + 0) * GATES + gr];
    float xv1 = xg[(size_t)(bb + 1) * GATES + gr];
    float xv2 = xg[(size_t)(bb + 2) * GATES + gr];
    float xv3 = xg[(size_t)(bb + 3) * GATES + gr];

    __syncthreads();                    // Bs staged

    const bf16* bbase = &Bs[l16 * 1032 + quad * 8];

    for (int tt = 0; tt < TCHUNK; ++tt) {
        const bf16* hin  = hrot + (size_t)tt * BH;
        bf16*       hout = hrot + (size_t)((tt + 1) & (TCHUNK - 1)) * BH;

        f32x4 acc0 = {xv0, xv1, xv2, xv3};      // chain 0 carries the xin C-init
        f32x4 acc1 = {0.f, 0.f, 0.f, 0.f};
        f32x4 acc2 = {0.f, 0.f, 0.f, 0.f};
        f32x4 acc3 = {0.f, 0.f, 0.f, 0.f};

        const bf16* aptr = hin + (size_t)(m0 + l16) * HID + quad * 8;
        #pragma unroll
        for (int q = 0; q < 8; ++q) {
            const int k0 = q * 32;
            bf16x8 a0 = *(const bf16x8*)(aptr + k0);
            bf16x8 b0 = *(const bf16x8*)(bbase + k0);
            acc0 = __builtin_amdgcn_mfma_f32_16x16x32_bf16(a0, b0, acc0, 0, 0, 0);
            bf16x8 a1 = *(const bf16x8*)(aptr + 256 + k0);
            bf16x8 b1 = *(const bf16x8*)(bbase + 256 + k0);
            acc1 = __builtin_amdgcn_mfma_f32_16x16x32_bf16(a1, b1, acc1, 0, 0, 0);
            bf16x8 a2 = *(const bf16x8*)(aptr + 512 + k0);
            bf16x8 b2 = *(const bf16x8*)(bbase + 512 + k0);
            acc2 = __builtin_amdgcn_mfma_f32_16x16x32_bf16(a2, b2, acc2, 0, 0, 0);
            bf16x8 a3 = *(const bf16x8*)(aptr + 768 + k0);
            bf16x8 b3 = *(const bf16x8*)(bbase + 768 + k0);
            acc3 = __builtin_amdgcn_mfma_f32_16x16x32_bf16(a3, b3, acc3, 0, 0, 0);
        }

        // prefetch next step's xin (hides LLC latency under exchange/act)
        if (tt + 1 < TCHUNK) {
            const float* xn = xg + (size_t)(tt + 1) * BATCH * GATES;
            xv0 = xn[(size_t)(bb + 0) * GATES + gr];
            xv1 = xn[(size_t)(bb + 1) * GATES + gr];
            xv2 = xn[(size_t)(bb + 2) * GATES + gr];
            xv3 = xn[(size_t)(bb + 3) * GATES + gr];
        }

        f32x4 g4 = (acc0 + acc1) + (acc2 + acc3);

        // intra-wave gate exchange (per-wave sg region; DS in-order per wave)
        #pragma unroll
        for (int r = 0; r < 4; ++r)
            sg[wv * 272 + (quad * 4 + r) * 17 + l16] = g4[r];
        const float* gp = &sg[wv * 272 + l16 * 17];
        float gi = gp[quad], gf = gp[4 + quad], gg = gp[8 + quad], go = gp[12 + quad];

        float si  = 1.f / (1.f + expf(-gi));
        float sf_ = 1.f / (1.f + expf(-gf));
        float so  = 1.f / (1.f + expf(-go));
        float cv  = sf_ * c + si * tanhf(gg);
        float hv  = so * tanhf(cv);
        c = cv;

        const int t = t0 + tt;
        const size_t idx = (size_t)cb * HID + cu;
        bf16 hb = (bf16)hv;

        // pack adjacent units (quad, quad+1) -> one 4B write-through store
        float hvn = __shfl_xor(hv, 16);
        if ((quad & 1) == 0) {
            bf16 hbn = (bf16)hvn;
            unsigned pk = (unsigned)__builtin_bit_cast(unsigned short, hb) |
                          ((unsigned)__builtin_bit_cast(unsigned short, hbn) << 16);
            __hip_atomic_store((unsigned*)(hout + idx), pk,
                               __ATOMIC_RELAXED, __HIP_MEMORY_SCOPE_AGENT);
        }
        if (seq_bf)  seq_bf[(size_t)t * BH + idx] = hb;
        if (seq_f32) seq_f32[(size_t)t * BH + idx] = hv;
        if (t == T_LEN - 1) hf32[idx] = hv;

        // lightweight grid barrier (no wbl2/inv needed: rotating buffer)
        if (tt != TCHUNK - 1) {
            asm volatile("s_waitcnt vmcnt(0)" ::: "memory");  // per-wave drain
            __syncthreads();
            if (tid == 0) {
                __hip_atomic_fetch_add(bar, 1u, __ATOMIC_RELAXED,
                                       __HIP_MEMORY_SCOPE_AGENT);
                const unsigned tgt = (unsigned)(tt + 1) * RBLK;
                unsigned guard = 0;
                while (__hip_atomic_load(bar, __ATOMIC_RELAXED,
                                         __HIP_MEMORY_SCOPE_AGENT) < tgt) {
                    __builtin_amdgcn_s_sleep(2);
                    if (++guard > (1u << 20)) break;   // hang-safety valve:
                }                                      // degrade to wrong answer
            }
            __syncthreads();
        }
    }

    cbuf[(size_t)cb * HID + cu] = c;    // normal store; kernel-end release
}

// ---------------------------------------------------------------------------
extern "C" void kernel_launch(void* const* d_in, const int* in_sizes, int n_in,
                              void* d_out, int out_size, void* d_ws, size_t ws_size,
                              hipStream_t stream) {
    const float* x    = (const float*)d_in[0];
    const float* w_ih = (const float*)d_in[1];
    const float* w_hh = (const float*)d_in[2];
    const float* b_ih = (const float*)d_in[3];
    const float* b_hh = (const float*)d_in[4];
    float* out = (float*)d_out;

    // ws layout:
    //   xin    : TCHUNK*B*4H fp32 = 64 MB
    //   cbuf   : B*H fp32, hf32: B*H fp32
    //   seq1bf : T*B*H bf16 = 64 MB   (layer-0 output, layer-1 GEMM input)
    //   wibf   : 4H*I bf16, whbf: 4H*H bf16 (per-layer reuse)
    //   hrot   : TCHUNK*B*H bf16 = 8 MB (rotating h slots)
    //   bar    : 1 unsigned
    float* xin  = (float*)d_ws;
    float* cbuf = xin + (size_t)TCHUNK * BATCH * GATES;
    float* hf32 = cbuf + (size_t)BATCH * HID;
    bf16* seq1bf = (bf16*)(hf32 + (size_t)BATCH * HID);
    bf16* wibf   = seq1bf + (size_t)T_LEN * BATCH * HID;
    bf16* whbf   = wibf + (size_t)GATES * IN_DIM;
    bf16* hrot   = whbf + (size_t)GATES * HID;
    unsigned* bar = (unsigned*)(hrot + (size_t)TCHUNK * BATCH * HID);

    const size_t seqE = (size_t)T_LEN * BATCH * HID;
    const size_t BHs  = (size_t)BATCH * HID;

    for (int l = 0; l < NLAYERS; ++l) {
        const float* wi = w_ih + (size_t)l * GATES * IN_DIM;
        const float* wh = w_hh + (size_t)l * GATES * HID;
        const float* bi = b_ih + (size_t)l * GATES;
        const float* bh = b_hh + (size_t)l * GATES;

        // weights -> bf16 (per-layer buffers, reused across layers)
        cvt_bf16<<<(GATES * IN_DIM / 4 + 255) / 256, 256, 0, stream>>>(wi, wibf, GATES * IN_DIM / 4);
        cvt_bf16<<<(GATES * HID / 4 + 255) / 256, 256, 0, stream>>>(wh, whbf, GATES * HID / 4);

        hipMemsetAsync(hrot, 0, BHs * sizeof(bf16), stream);       // slot 0: h(-1)=0
        hipMemsetAsync(cbuf, 0, BHs * sizeof(float), stream);      // c(-1)=0

        for (int ch = 0; ch < T_LEN / TCHUNK; ++ch) {
            // input projection for this chunk: [4096 x 4096 x 1024]
            if (l == 0) {
                const float* Ab = x + (size_t)ch * TCHUNK * BATCH * IN_DIM;
                gemm_xin<true><<<dim3(GATES / 128, TCHUNK * BATCH / 128), 256, 0, stream>>>(
                    Ab, wibf, bi, bh, xin);
            } else {
                const bf16* Ab = seq1bf + (size_t)ch * TCHUNK * BATCH * HID;
                gemm_xin<false><<<dim3(GATES / 128, TCHUNK * BATCH / 128), 256, 0, stream>>>(
                    Ab, wibf, bi, bh, xin);
            }
            // persistent recurrence over the 64 timesteps of this chunk
            hipMemsetAsync(bar, 0, sizeof(unsigned), stream);
            int t0 = ch * TCHUNK;
            const bf16*  whc = whbf;
            const float* xgc = xin;
            bf16*  sb = (l == 0) ? seq1bf : nullptr;
            float* sf = (l == 1) ? out : nullptr;
            void* args[9] = { (void*)&whc, (void*)&xgc, (void*)&cbuf, (void*)&hf32,
                              (void*)&hrot, (void*)&sb, (void*)&sf, (void*)&bar,
                              (void*)&t0 };
            hipLaunchCooperativeKernel((void*)lstm_chunk, dim3(RBLK), dim3(256),
                                       args, 0, stream);
        }
        hipMemcpyAsync(out + seqE + (size_t)l * BHs, hf32, BHs * sizeof(float),
                       hipMemcpyDeviceToDevice, stream);
        hipMemcpyAsync(out + seqE + (size_t)(NLAYERS + l) * BHs, cbuf, BHs * sizeof(float),
                       hipMemcpyDeviceToDevice, stream);
    }
}

// Round 6
// 8864.807 us; speedup vs baseline: 1.9490x; 1.3940x over previous
//
#include <hip/hip_runtime.h>
#include <cstddef>
#include <cstdint>

// CustomLSTM: T=512, B=64, I=H=1024, L=2. fp32 in/out, bf16 MFMA internally.
#define T_LEN   512
#define BATCH   64
#define IN_DIM  1024
#define HID     1024
#define GATES   4096
#define NLAYERS 2
#define TCHUNK  64
#define BH      (BATCH * HID)
#define RBLK    256             // persistent-recurrence blocks; 4 hidden units each

typedef __bf16 bf16;
typedef __bf16 bf16x8 __attribute__((ext_vector_type(8)));
typedef float  f32x4  __attribute__((ext_vector_type(4)));

// ---------------------------------------------------------------------------
// fp32 -> bf16 (RNE), vectorized. n4 = n/4.
// ---------------------------------------------------------------------------
__global__ __launch_bounds__(256) void cvt_bf16(const float* __restrict__ in,
                                                bf16* __restrict__ out, int n4) {
    int i = blockIdx.x * blockDim.x + threadIdx.x;
    if (i >= n4) return;
    float4 v = ((const float4*)in)[i];
    bf16 o[4] = {(bf16)v.x, (bf16)v.y, (bf16)v.z, (bf16)v.w};
    *(uint2*)(out + 4 * (size_t)i) = *(uint2*)o;
}

// ---------------------------------------------------------------------------
// Input projection GEMM (NT, bf16 MFMA): C[m][n] = A[m][:]·W[n][:] + bias[n]
// M=TCHUNK*B=4096, N=GATES=4096, K=1024. 128x128 tile, BK=32, 256 thr, 4 waves
// each computing 64x64 as 4x4 grid of mfma_f32_16x16x32_bf16.
// ---------------------------------------------------------------------------
template <bool AF32>
__global__ __launch_bounds__(256) void gemm_xin(
    const void* __restrict__ Aptr, const bf16* __restrict__ W,
    const float* __restrict__ bih, const float* __restrict__ bhh,
    float* __restrict__ C)
{
    __shared__ bf16 As[128 * 40];   // [m][k], pad 32->40 breaks b128 conflicts
    __shared__ bf16 Bs[128 * 40];   // [n][k]

    const int m0 = blockIdx.y * 128;
    const int n0 = blockIdx.x * 128;
    const int tid  = threadIdx.x;
    const int lane = tid & 63;
    const int wv   = tid >> 6;          // 0..3
    const int wm   = (wv & 1) * 64;
    const int wn   = (wv >> 1) * 64;
    const int quad = lane >> 4;         // 0..3
    const int l16  = lane & 15;

    f32x4 acc[4][4] = {};

    for (int k0 = 0; k0 < IN_DIM; k0 += 32) {
        if constexpr (AF32) {
            const float* A = (const float*)Aptr;
            const int row = tid >> 3;            // 0..31
            const int ko  = (tid & 7) * 4;       // 0..28
            #pragma unroll
            for (int p = 0; p < 4; ++p) {
                int r = row + 32 * p;
                float4 v = *(const float4*)(A + (size_t)(m0 + r) * IN_DIM + k0 + ko);
                bf16 o[4] = {(bf16)v.x, (bf16)v.y, (bf16)v.z, (bf16)v.w};
                *(uint2*)&As[r * 40 + ko] = *(uint2*)o;
            }
        } else {
            const bf16* A = (const bf16*)Aptr;
            const int row = tid >> 2;            // 0..63
            const int ko  = (tid & 3) * 8;       // 0,8,16,24
            *(uint4*)&As[row * 40 + ko] =
                *(const uint4*)(A + (size_t)(m0 + row) * IN_DIM + k0 + ko);
            *(uint4*)&As[(row + 64) * 40 + ko] =
                *(const uint4*)(A + (size_t)(m0 + row + 64) * IN_DIM + k0 + ko);
        }
        {
            const int row = tid >> 2;
            const int ko  = (tid & 3) * 8;
            *(uint4*)&Bs[row * 40 + ko] =
                *(const uint4*)(W + (size_t)(n0 + row) * IN_DIM + k0 + ko);
            *(uint4*)&Bs[(row + 64) * 40 + ko] =
                *(const uint4*)(W + (size_t)(n0 + row + 64) * IN_DIM + k0 + ko);
        }
        __syncthreads();

        bf16x8 af[4], bfr[4];
        #pragma unroll
        for (int t = 0; t < 4; ++t) {
            af[t]  = *(const bf16x8*)&As[(wm + t * 16 + l16) * 40 + quad * 8];
            bfr[t] = *(const bf16x8*)&Bs[(wn + t * 16 + l16) * 40 + quad * 8];
        }
        #pragma unroll
        for (int mt = 0; mt < 4; ++mt)
            #pragma unroll
            for (int nt = 0; nt < 4; ++nt)
                acc[mt][nt] = __builtin_amdgcn_mfma_f32_16x16x32_bf16(
                    af[mt], bfr[nt], acc[mt][nt], 0, 0, 0);
        __syncthreads();
    }

    #pragma unroll
    for (int nt = 0; nt < 4; ++nt) {
        int col = n0 + wn + nt * 16 + l16;
        float bias = bih[col] + bhh[col];
        #pragma unroll
        for (int mt = 0; mt < 4; ++mt) {
            #pragma unroll
            for (int r = 0; r < 4; ++r) {
                int row = m0 + wm + mt * 16 + quad * 4 + r;
                C[(size_t)row * GATES + col] = acc[mt][nt][r] + bias;
            }
        }
    }
}

// ---------------------------------------------------------------------------
// Persistent recurrence — round-3 datapath VERBATIM (hardware-validated:
// passed absmax 0.0100), detector barrier with TIGHT guards (2^16: any
// livelock completes in ~20 s as a wrong answer, never a container-killing
// timeout; normal poll counts are ~10 iterations, 4 orders below the guard).
// 256 blocks (cooperative); block bk owns hidden units j0=4bk..+3 -> 16 gate
// rows, staged in LDS ONCE per 64-step chunk.
// Per step: 1 MFMA col-tile per wave, K split into 4 independent chains.
// Gate exchange via per-wave sg region. c state in registers.
// Cross-block h: 64-slot rotating buffer + relaxed agent write-through
// stores + vmcnt drain (validated in round 3).
// Barrier:
//  - arrival: each block's tid0 plain-stores epoch to its OWN flag word
//    (parallel; no RMW serialization at one LLC line),
//  - detector: wave 0 of block 0 scans the 256 flags (4 loads/lane + __all),
//    then stores the epoch to a RELEASE word on a different 128B line,
//  - everyone polls only the write-once release word (read-sharing, no RMW).
// Flags are zeroed before each launch (pattern validated by round 3: its
// counter barrier depended on the same memset and passed), epochs are
// monotone within a launch -> early release impossible.
// ---------------------------------------------------------------------------
__global__ __launch_bounds__(256) void lstm_chunk(
    const bf16*  __restrict__ wh,      // [4H][H] bf16
    const float* __restrict__ xg,      // [TCHUNK][B][4H] fp32
    float*       __restrict__ cbuf,    // [B][H]
    float*       __restrict__ hf32,    // [B][H] (written at t==T_LEN-1 only)
    bf16*        __restrict__ hrot,    // [TCHUNK][B][H] rotating h
    bf16*        __restrict__ seq_bf,  // [T][B][H] or null (layer 0)
    float*       __restrict__ seq_f32, // [T][B][H] or null (layer 1)
    unsigned*    __restrict__ bar,     // [512] zeroed: flags[0..255], release at [384]
    int t0)
{
    __shared__ bf16  Bs[16 * 1032];    // wh slice, pad 1024->1032
    __shared__ float sg[4 * 272];      // per-wave gate tile, stride 17

    const int bk   = blockIdx.x;
    const int j0   = bk * 4;
    const int tid  = threadIdx.x;
    const int lane = tid & 63;
    const int wv   = tid >> 6;
    const int m0   = wv * 16;          // batch base for this wave
    const int quad = lane >> 4;
    const int l16  = lane & 15;

    unsigned* flags   = bar;
    unsigned* release = bar + 384;     // different 128B line than flags

    // stage wh rows once: local row = type*4+u -> gate row type*1024 + j0 + u
    #pragma unroll
    for (int i = 0; i < 8; ++i) {
        int flat = i * 256 + tid;       // 0..2047 (16 rows x 128 uint4)
        int row  = flat >> 7;
        int k16  = flat & 127;
        int grr  = (row >> 2) * 1024 + j0 + (row & 3);
        *(uint4*)&Bs[row * 1032 + k16 * 8] =
            *(const uint4*)(wh + (size_t)grr * HID + k16 * 8);
    }

    // this thread's cell: batch cb, unit cu (one cell per thread, all steps)
    const int cb = m0 + l16;
    const int cu = j0 + quad;
    float c = cbuf[(size_t)cb * HID + cu];

    // MFMA D mapping: row = quad*4+r (batch bb+r), col = l16 -> gate row gr
    const int gr = (l16 >> 2) * 1024 + j0 + (l16 & 3);
    const int bb = m0 + quad * 4;

    // prologue xin for tt=0 (prefetched one step ahead thereafter)
    float xv0 = xg[(size_t)(bb + 0) * GATES + gr];
    float xv1 = xg[(size_t)(bb + 1) * GATES + gr];
    float xv2 = xg[(size_t)(bb + 2) * GATES + gr];
    float xv3 = xg[(size_t)(bb + 3) * GATES + gr];

    __syncthreads();                    // Bs staged

    const bf16* bbase = &Bs[l16 * 1032 + quad * 8];

    for (int tt = 0; tt < TCHUNK; ++tt) {
        const bf16* hin  = hrot + (size_t)tt * BH;
        bf16*       hout = hrot + (size_t)((tt + 1) & (TCHUNK - 1)) * BH;

        f32x4 acc0 = {xv0, xv1, xv2, xv3};      // chain 0 carries the xin C-init
        f32x4 acc1 = {0.f, 0.f, 0.f, 0.f};
        f32x4 acc2 = {0.f, 0.f, 0.f, 0.f};
        f32x4 acc3 = {0.f, 0.f, 0.f, 0.f};

        const bf16* aptr = hin + (size_t)(m0 + l16) * HID + quad * 8;
        #pragma unroll
        for (int q = 0; q < 8; ++q) {
            const int k0 = q * 32;
            bf16x8 a0 = *(const bf16x8*)(aptr + k0);
            bf16x8 b0 = *(const bf16x8*)(bbase + k0);
            acc0 = __builtin_amdgcn_mfma_f32_16x16x32_bf16(a0, b0, acc0, 0, 0, 0);
            bf16x8 a1 = *(const bf16x8*)(aptr + 256 + k0);
            bf16x8 b1 = *(const bf16x8*)(bbase + 256 + k0);
            acc1 = __builtin_amdgcn_mfma_f32_16x16x32_bf16(a1, b1, acc1, 0, 0, 0);
            bf16x8 a2 = *(const bf16x8*)(aptr + 512 + k0);
            bf16x8 b2 = *(const bf16x8*)(bbase + 512 + k0);
            acc2 = __builtin_amdgcn_mfma_f32_16x16x32_bf16(a2, b2, acc2, 0, 0, 0);
            bf16x8 a3 = *(const bf16x8*)(aptr + 768 + k0);
            bf16x8 b3 = *(const bf16x8*)(bbase + 768 + k0);
            acc3 = __builtin_amdgcn_mfma_f32_16x16x32_bf16(a3, b3, acc3, 0, 0, 0);
        }

        // prefetch next step's xin (hides LLC latency under exchange/act)
        if (tt + 1 < TCHUNK) {
            const float* xn = xg + (size_t)(tt + 1) * BATCH * GATES;
            xv0 = xn[(size_t)(bb + 0) * GATES + gr];
            xv1 = xn[(size_t)(bb + 1) * GATES + gr];
            xv2 = xn[(size_t)(bb + 2) * GATES + gr];
            xv3 = xn[(size_t)(bb + 3) * GATES + gr];
        }

        f32x4 g4 = (acc0 + acc1) + (acc2 + acc3);

        // intra-wave gate exchange (per-wave sg region; DS in-order per wave)
        #pragma unroll
        for (int r = 0; r < 4; ++r)
            sg[wv * 272 + (quad * 4 + r) * 17 + l16] = g4[r];
        const float* gp = &sg[wv * 272 + l16 * 17];
        float gi = gp[quad], gf = gp[4 + quad], gg = gp[8 + quad], go = gp[12 + quad];

        float si  = 1.f / (1.f + expf(-gi));
        float sf_ = 1.f / (1.f + expf(-gf));
        float so  = 1.f / (1.f + expf(-go));
        float cv  = sf_ * c + si * tanhf(gg);
        float hv  = so * tanhf(cv);
        c = cv;

        const int t = t0 + tt;
        const size_t idx = (size_t)cb * HID + cu;
        bf16 hb = (bf16)hv;

        // pack adjacent units (quad, quad+1) -> one 4B write-through store
        float hvn = __shfl_xor(hv, 16);
        if ((quad & 1) == 0) {
            bf16 hbn = (bf16)hvn;
            unsigned pk = (unsigned)__builtin_bit_cast(unsigned short, hb) |
                          ((unsigned)__builtin_bit_cast(unsigned short, hbn) << 16);
            __hip_atomic_store((unsigned*)(hout + idx), pk,
                               __ATOMIC_RELAXED, __HIP_MEMORY_SCOPE_AGENT);
        }
        if (seq_bf)  seq_bf[(size_t)t * BH + idx] = hb;
        if (seq_f32) seq_f32[(size_t)t * BH + idx] = hv;
        if (t == T_LEN - 1) hf32[idx] = hv;

        // ---- contention-free grid barrier ----
        if (tt != TCHUNK - 1) {
            const unsigned ep = (unsigned)(tt + 1);
            asm volatile("s_waitcnt vmcnt(0)" ::: "memory");  // drain h stores
            __syncthreads();
            if (tid == 0)
                __hip_atomic_store(flags + bk, ep,
                                   __ATOMIC_RELAXED, __HIP_MEMORY_SCOPE_AGENT);
            if (bk == 0 && tid < 64) {            // detector wave
                unsigned guard = 0;
                for (;;) {
                    unsigned f0 = __hip_atomic_load(flags + tid,
                                   __ATOMIC_RELAXED, __HIP_MEMORY_SCOPE_AGENT);
                    unsigned f1 = __hip_atomic_load(flags + 64 + tid,
                                   __ATOMIC_RELAXED, __HIP_MEMORY_SCOPE_AGENT);
                    unsigned f2 = __hip_atomic_load(flags + 128 + tid,
                                   __ATOMIC_RELAXED, __HIP_MEMORY_SCOPE_AGENT);
                    unsigned f3 = __hip_atomic_load(flags + 192 + tid,
                                   __ATOMIC_RELAXED, __HIP_MEMORY_SCOPE_AGENT);
                    if (__all(f0 >= ep && f1 >= ep && f2 >= ep && f3 >= ep)) break;
                    __builtin_amdgcn_s_sleep(1);
                    if (++guard > (1u << 16)) break;   // hang-safety valve:
                }                                      // degrade to wrong answer
                if (tid == 0)
                    __hip_atomic_store(release, ep,
                                       __ATOMIC_RELAXED, __HIP_MEMORY_SCOPE_AGENT);
            }
            if (tid == 0) {
                unsigned guard = 0;
                while (__hip_atomic_load(release, __ATOMIC_RELAXED,
                                         __HIP_MEMORY_SCOPE_AGENT) < ep) {
                    __builtin_amdgcn_s_sleep(1);
                    if (++guard > (1u << 16)) break;   // hang-safety valve
                }
            }
            __syncthreads();
        }
    }

    cbuf[(size_t)cb * HID + cu] = c;    // normal store; kernel-end release
}

// ---------------------------------------------------------------------------
extern "C" void kernel_launch(void* const* d_in, const int* in_sizes, int n_in,
                              void* d_out, int out_size, void* d_ws, size_t ws_size,
                              hipStream_t stream) {
    const float* x    = (const float*)d_in[0];
    const float* w_ih = (const float*)d_in[1];
    const float* w_hh = (const float*)d_in[2];
    const float* b_ih = (const float*)d_in[3];
    const float* b_hh = (const float*)d_in[4];
    float* out = (float*)d_out;

    // ws layout:
    //   xin    : TCHUNK*B*4H fp32 = 64 MB
    //   cbuf   : B*H fp32, hf32: B*H fp32
    //   seq1bf : T*B*H bf16 = 64 MB   (layer-0 output, layer-1 GEMM input)
    //   wibf   : 4H*I bf16, whbf: 4H*H bf16 (per-layer reuse)
    //   hrot   : TCHUNK*B*H bf16 = 8 MB (rotating h slots)
    //   bar    : 512 unsigned (flags[0..255] + release[384])
    float* xin  = (float*)d_ws;
    float* cbuf = xin + (size_t)TCHUNK * BATCH * GATES;
    float* hf32 = cbuf + (size_t)BATCH * HID;
    bf16* seq1bf = (bf16*)(hf32 + (size_t)BATCH * HID);
    bf16* wibf   = seq1bf + (size_t)T_LEN * BATCH * HID;
    bf16* whbf   = wibf + (size_t)GATES * IN_DIM;
    bf16* hrot   = whbf + (size_t)GATES * HID;
    unsigned* bar = (unsigned*)(hrot + (size_t)TCHUNK * BATCH * HID);

    const size_t seqE = (size_t)T_LEN * BATCH * HID;
    const size_t BHs  = (size_t)BATCH * HID;

    for (int l = 0; l < NLAYERS; ++l) {
        const float* wi = w_ih + (size_t)l * GATES * IN_DIM;
        const float* wh = w_hh + (size_t)l * GATES * HID;
        const float* bi = b_ih + (size_t)l * GATES;
        const float* bh = b_hh + (size_t)l * GATES;

        // weights -> bf16 (per-layer buffers, reused across layers)
        cvt_bf16<<<(GATES * IN_DIM / 4 + 255) / 256, 256, 0, stream>>>(wi, wibf, GATES * IN_DIM / 4);
        cvt_bf16<<<(GATES * HID / 4 + 255) / 256, 256, 0, stream>>>(wh, whbf, GATES * HID / 4);

        hipMemsetAsync(hrot, 0, BHs * sizeof(bf16), stream);       // slot 0: h(-1)=0
        hipMemsetAsync(cbuf, 0, BHs * sizeof(float), stream);      // c(-1)=0

        for (int ch = 0; ch < T_LEN / TCHUNK; ++ch) {
            // input projection for this chunk: [4096 x 4096 x 1024]
            if (l == 0) {
                const float* Ab = x + (size_t)ch * TCHUNK * BATCH * IN_DIM;
                gemm_xin<true><<<dim3(GATES / 128, TCHUNK * BATCH / 128), 256, 0, stream>>>(
                    Ab, wibf, bi, bh, xin);
            } else {
                const bf16* Ab = seq1bf + (size_t)ch * TCHUNK * BATCH * HID;
                gemm_xin<false><<<dim3(GATES / 128, TCHUNK * BATCH / 128), 256, 0, stream>>>(
                    Ab, wibf, bi, bh, xin);
            }
            // persistent recurrence over the 64 timesteps of this chunk
            hipMemsetAsync(bar, 0, 512 * sizeof(unsigned), stream);
            int t0 = ch * TCHUNK;
            const bf16*  whc = whbf;
            const float* xgc = xin;
            bf16*  sb = (l == 0) ? seq1bf : nullptr;
            float* sf = (l == 1) ? out : nullptr;
            void* args[9] = { (void*)&whc, (void*)&xgc, (void*)&cbuf, (void*)&hf32,
                              (void*)&hrot, (void*)&sb, (void*)&sf, (void*)&bar,
                              (void*)&t0 };
            hipLaunchCooperativeKernel((void*)lstm_chunk, dim3(RBLK), dim3(256),
                                       args, 0, stream);
        }
        hipMemcpyAsync(out + seqE + (size_t)l * BHs, hf32, BHs * sizeof(float),
                       hipMemcpyDeviceToDevice, stream);
        hipMemcpyAsync(out + seqE + (size_t)(NLAYERS + l) * BHs, cbuf, BHs * sizeof(float),
                       hipMemcpyDeviceToDevice, stream);
    }
}